// Round 4
// baseline (1330.855 us; speedup 1.0000x reference)
//
#include <hip/hip_runtime.h>

// PNLM: patch (15x15) non-local attention + projection + residual.
// k_qk  : R1-proven projection kernel; outputs interleaved qkws[hw][Q160|K160]
//         bf16 rows (640B), cols 144..159 of each half are stored zeros.
// k_attn: per patch block: att^T via MFMA with Q/K frags straight from global
//         rows (no masking needed), lane-local softmax, PV over c-halves,
//         projection from fp32 wproj via LDS sixteenths, fp32 residual.

typedef __bf16 bf16x8 __attribute__((ext_vector_type(8)));
typedef float  f32x4  __attribute__((ext_vector_type(4)));

#define MFMA(a,b,c) __builtin_amdgcn_mfma_f32_16x16x32_bf16((a),(b),(c),0,0,0)

#define QK_ROW 320            // Q cols 0..159 (144+ zero), K cols 160..319 (144+ zero)

__device__ __forceinline__ unsigned short f2bf(float f){
  union { float f; unsigned int u; } v; v.f = f;
  unsigned int r = v.u + 0x7FFFu + ((v.u >> 16) & 1u);   // RNE
  return (unsigned short)(r >> 16);
}
// 16B-block XOR swizzle for [rows][256] bf16 LDS tiles (write&read same involution).
__device__ __forceinline__ int swz(int row, int col){
  return row*256 + ((((col >> 3) ^ (row & 7)) << 3) | (col & 7));
}
__device__ __forceinline__ bf16x8 ld_frag_lds(const unsigned short* p, int idx){
  uint4 v = *(const uint4*)(p + idx);
  return __builtin_bit_cast(bf16x8, v);
}
__device__ __forceinline__ bf16x8 ld_frag_b(const void* p){
  uint4 v = *(const uint4*)p;
  return __builtin_bit_cast(bf16x8, v);
}

// D-layout (col=lane&15, rows 4*(lane>>4)+jj per 16-tile) -> operand-frag layout.
__device__ __forceinline__ void repack_frag(const unsigned int* plo, const unsigned int* phi,
                                            uint4* outf, int lane){
  const int nn = lane & 15, hh = lane >> 4;
  const int sla = nn + 32*(hh & 1);
  const int slb = sla + 16;
  const bool up = hh >= 2;
  #pragma unroll
  for (int k = 0; k < 8; ++k){
    unsigned int a0 = (unsigned int)__shfl((int)plo[2*k],   sla);
    unsigned int a1 = (unsigned int)__shfl((int)plo[2*k+1], sla);
    unsigned int b0 = (unsigned int)__shfl((int)phi[2*k],   sla);
    unsigned int b1 = (unsigned int)__shfl((int)phi[2*k+1], sla);
    unsigned int c0 = (unsigned int)__shfl((int)plo[2*k],   slb);
    unsigned int c1 = (unsigned int)__shfl((int)plo[2*k+1], slb);
    unsigned int d0 = (unsigned int)__shfl((int)phi[2*k],   slb);
    unsigned int d1 = (unsigned int)__shfl((int)phi[2*k+1], slb);
    outf[k] = make_uint4(up?a1:a0, up?b1:b0, up?c1:c0, up?d1:d0);
  }
}

// ---------------- kernel 1: QK projections (R1-proven, layout diff only) -----
__global__ __launch_bounds__(512) void k_qk(
    const float* __restrict__ x, const float* __restrict__ wq,
    const float* __restrict__ wk,
    unsigned short* __restrict__ qkws)
{
  __shared__ unsigned short xt [128*256];  // X^T tile [hw][c], swizzled
  __shared__ unsigned short wqs[ 32*256];  // wq rows  [e ][c], swizzled
  __shared__ unsigned short wks[ 32*256];
  const int wg  = blockIdx.x;
  const int b   = wg / 450;
  const int hw0 = (wg % 450) * 128;
  const int tid = threadIdx.x;
  const int lane = tid & 63, wave = tid >> 6;
  const int col  = lane & 15, hi = lane >> 4;

  { // stage X^T (fp32 -> bf16), coalesced reads over hw
    const float* xb = x + (size_t)b * 256 * 57600 + hw0;
    const int hw_l = tid & 127;
    #pragma unroll 4
    for (int i = 0; i < 32; ++i){
      int cp = (tid >> 7) * 32 + i;      // 0..127
      int c  = cp * 2;
      float f0 = xb[(size_t)c     * 57600 + hw_l];
      float f1 = xb[(size_t)(c+1) * 57600 + hw_l];
      *(unsigned int*)(&xt[swz(hw_l, c)]) =
          (unsigned int)f2bf(f0) | ((unsigned int)f2bf(f1) << 16);
    }
  }
  __syncthreads();

  bf16x8 af[8];                          // A-frags: this wave's 16 hw rows
  const int arow = wave*16 + col;
  #pragma unroll
  for (int k = 0; k < 8; ++k)
    af[k] = ld_frag_lds(xt, swz(arow, k*32 + hi*8));

  const size_t orow_base = (size_t)b*57600 + hw0 + wave*16;

  for (int eg = 0; eg < 5; ++eg){        // e-groups of 32 (e_pad=160, zeros>=144)
    __syncthreads();
    for (int i = 0; i < 8; ++i){
      int idx = tid + i*512;             // 0..4095
      int e_l = idx >> 7, c = (idx & 127) * 2;
      int e = eg*32 + e_l;
      float2 vq = make_float2(0.f,0.f), vk = make_float2(0.f,0.f);
      if (e < 144){
        vq = *(const float2*)(wq + (size_t)e*256 + c);
        vk = *(const float2*)(wk + (size_t)e*256 + c);
      }
      *(unsigned int*)(&wqs[swz(e_l, c)]) =
          (unsigned int)f2bf(vq.x) | ((unsigned int)f2bf(vq.y) << 16);
      *(unsigned int*)(&wks[swz(e_l, c)]) =
          (unsigned int)f2bf(vk.x) | ((unsigned int)f2bf(vk.y) << 16);
    }
    __syncthreads();
    #pragma unroll
    for (int etl = 0; etl < 2; ++etl){
      f32x4 aq = {0.f,0.f,0.f,0.f}, ak = {0.f,0.f,0.f,0.f};
      const int el = etl*16 + col;
      #pragma unroll
      for (int k = 0; k < 8; ++k){
        int idx = swz(el, k*32 + hi*8);
        bf16x8 bq = ld_frag_lds(wqs, idx);
        bf16x8 bk = ld_frag_lds(wks, idx);
        aq = MFMA(af[k], bq, aq);
        ak = MFMA(af[k], bk, ak);
      }
      const int e_out = eg*32 + etl*16 + col;
      #pragma unroll
      for (int jj = 0; jj < 4; ++jj){
        size_t row = orow_base + hi*4 + jj;
        qkws[row*QK_ROW + e_out]       = f2bf(aq[jj]);
        qkws[row*QK_ROW + 160 + e_out] = f2bf(ak[jj]);
      }
    }
  }
}

// ---------------- kernel 2: attention + PV + proj + residual -----------------
__global__ __launch_bounds__(512,4) void k_attn(
    const float* __restrict__ x, const float* __restrict__ wproj,
    const unsigned short* __restrict__ qkws, float* __restrict__ out)
{
  // xl[128][256] (65,536B) | wl[16][256] (8,192B) | hwp LUT (960B) = 74,688B
  __shared__ __align__(16) unsigned short S[32768 + 4096 + 480];
  unsigned short* xl = S;
  unsigned short* wl = S + 32768;
  unsigned int*  hwp = (unsigned int*)(S + 32768 + 4096);
  const int wg = blockIdx.x;
  const int b  = wg >> 8;
  const int th = (wg >> 4) & 15, tw = wg & 15;
  const int h0 = th*15, w0 = tw*15;
  const int tid = threadIdx.x;
  const int lane = tid & 63, wave = tid >> 6;
  const int col  = lane & 15, hi = lane >> 4;
  const size_t xbase = (size_t)b * 256 * 57600;
  const unsigned short* qkb = qkws + (size_t)b * 57600 * QK_ROW;

  if (tid < 240){
    int ms = tid <= 224 ? tid : 224;
    hwp[tid] = (unsigned int)((h0 + ms/15)*240 + w0 + ms%15);
  }
  __syncthreads();

  // ---- P1: att^T strips + lane-local softmax + register repack ----
  uint4 attf[2][8];
  #pragma unroll
  for (int slot = 0; slot < 2; ++slot){
    const int nt = wave + slot*8;
    if (nt < 15){
      const int n  = nt*16 + col;
      const int na = n <= 224 ? n : 224;          // clamp (garbage cols unused)
      const unsigned short* qrow = qkb + (size_t)hwp[na]*QK_ROW;
      bf16x8 qf[5];
      #pragma unroll
      for (int c = 0; c < 5; ++c)
        qf[c] = ld_frag_b(qrow + c*32 + hi*8);
      f32x4 at[15];
      #pragma unroll
      for (int T = 0; T < 15; ++T){
        int mr = T*16 + col;
        const unsigned short* krow =
            qkb + (size_t)hwp[mr <= 224 ? mr : 224]*QK_ROW + 160;
        f32x4 acc = {0.f,0.f,0.f,0.f};
        #pragma unroll
        for (int c = 0; c < 5; ++c)
          acc = MFMA(ld_frag_b(krow + c*32 + hi*8), qf[c], acc);  // att^T[m][n]
        at[T] = acc;
      }
      const float sc = 0.12022458674074695f;      // log2(e)/12
      float M = -3.0e38f;
      #pragma unroll
      for (int T = 0; T < 15; ++T){
        #pragma unroll
        for (int jj = 0; jj < 4; ++jj){
          int m = T*16 + hi*4 + jj;
          if (m <= 224) M = fmaxf(M, at[T][jj]*sc);
        }
      }
      M = fmaxf(M, __shfl_xor(M, 16));
      M = fmaxf(M, __shfl_xor(M, 32));
      float Ssum = 0.f;
      #pragma unroll
      for (int T = 0; T < 15; ++T){
        #pragma unroll
        for (int jj = 0; jj < 4; ++jj){
          int m = T*16 + hi*4 + jj;
          float v = (m <= 224) ? exp2f(at[T][jj]*sc - M) : 0.f;
          at[T][jj] = v; Ssum += v;
        }
      }
      Ssum += __shfl_xor(Ssum, 16);
      Ssum += __shfl_xor(Ssum, 32);
      const float inv = 1.0f / Ssum;
      unsigned int plo[16], phi[16];
      #pragma unroll
      for (int T = 0; T < 15; ++T){
        plo[T] = (unsigned int)f2bf(at[T][0]*inv) | ((unsigned int)f2bf(at[T][1]*inv) << 16);
        phi[T] = (unsigned int)f2bf(at[T][2]*inv) | ((unsigned int)f2bf(at[T][3]*inv) << 16);
      }
      plo[15] = 0u; phi[15] = 0u;
      repack_frag(plo, phi, attf[slot], lane);
    }
  }

  // ---- P2/P3: X staged by c-halves (xl[128][256] swizzled, m>224 zero);
  //             PV partials packed bf16 (half unrolled -> static y indices) ----
  unsigned int ylo[2][16], yhi[2][16];
  #pragma unroll
  for (int half = 0; half < 2; ++half){
    __syncthreads();                         // previous readers done
    for (int i = tid; i < 128*128; i += 512){
      int c = i >> 7, m = (i & 127)*2;
      float f0 = (m     <= 224) ? x[xbase + (size_t)(half*128 + c)*57600 + hwp[m]]   : 0.f;
      float f1 = (m + 1 <= 224) ? x[xbase + (size_t)(half*128 + c)*57600 + hwp[m+1]] : 0.f;
      *(unsigned int*)(&xl[swz(c, m)]) =
          (unsigned int)f2bf(f0) | ((unsigned int)f2bf(f1) << 16);
    }
    __syncthreads();
    #pragma unroll
    for (int slot = 0; slot < 2; ++slot){
      const int nt = wave + slot*8;
      if (nt < 15){
        #pragma unroll
        for (int ct = 0; ct < 8; ++ct){
          f32x4 acc = {0.f,0.f,0.f,0.f};
          #pragma unroll
          for (int k = 0; k < 8; ++k){
            bf16x8 xf = ld_frag_lds(xl, swz(ct*16 + col, k*32 + hi*8));
            acc = MFMA(xf, __builtin_bit_cast(bf16x8, attf[slot][k]), acc);
          }
          ylo[slot][half*8 + ct] = (unsigned int)f2bf(acc[0]) | ((unsigned int)f2bf(acc[1]) << 16);
          yhi[slot][half*8 + ct] = (unsigned int)f2bf(acc[2]) | ((unsigned int)f2bf(acc[3]) << 16);
        }
      }
    }
  }

  uint4 y1f[2][8];
  #pragma unroll
  for (int slot = 0; slot < 2; ++slot){
    const int nt = wave + slot*8;
    if (nt < 15)
      repack_frag(ylo[slot], yhi[slot], y1f[slot], lane);
  }

  // ---- P4: projection (wproj fp32 -> wl sixteenths) + fp32 residual ----
  #pragma unroll 1
  for (int oe = 0; oe < 16; ++oe){
    __syncthreads();                          // prev chunk's readers done
    for (int i = tid; i < 16*128; i += 512){
      int olr = i >> 7, c = (i & 127)*2;
      const float* wr = wproj + (size_t)(oe*16 + olr)*256 + c;
      *(unsigned int*)(&wl[swz(olr, c)]) =
          (unsigned int)f2bf(wr[0]) | ((unsigned int)f2bf(wr[1]) << 16);
    }
    __syncthreads();
    bf16x8 awf[8];
    #pragma unroll
    for (int k = 0; k < 8; ++k)
      awf[k] = ld_frag_lds(wl, swz(col, k*32 + hi*8));
    #pragma unroll
    for (int slot = 0; slot < 2; ++slot){
      const int nt = wave + slot*8;
      if (nt < 15){
        f32x4 y2 = {0.f,0.f,0.f,0.f};
        #pragma unroll
        for (int k = 0; k < 8; ++k)
          y2 = MFMA(awf[k], __builtin_bit_cast(bf16x8, y1f[slot][k]), y2);
        const int n = nt*16 + col;
        if (n <= 224){
          const size_t pix = hwp[n];
          #pragma unroll
          for (int jj = 0; jj < 4; ++jj){
            int o = oe*16 + hi*4 + jj;
            const size_t idx = xbase + (size_t)o*57600 + pix;
            out[idx] = y2[jj] + x[idx];
          }
        }
      }
    }
  }
}

extern "C" void kernel_launch(void* const* d_in, const int* in_sizes, int n_in,
                              void* d_out, int out_size, void* d_ws, size_t ws_size,
                              hipStream_t stream)
{
  const float* x     = (const float*)d_in[0];
  const float* wq    = (const float*)d_in[1];
  const float* wk    = (const float*)d_in[2];
  const float* wproj = (const float*)d_in[3];
  float* out = (float*)d_out;
  // workspace: qkws rows 8*57600 x 320 bf16 = 294,912,000 B (same as R1-proven)
  unsigned short* qkws = (unsigned short*)d_ws;
  (void)in_sizes; (void)n_in; (void)out_size; (void)ws_size;

  k_qk  <<<dim3(3600), dim3(512), 0, stream>>>(x, wq, wk, qkws);
  k_attn<<<dim3(2048), dim3(512), 0, stream>>>(x, wproj, qkws, out);
}

// Round 6
// 1143.288 us; speedup vs baseline: 1.1641x; 1.1641x over previous
//
#include <hip/hip_runtime.h>

// PNLM: patch (15x15) non-local attention + projection + residual.
// k_qk  : R1/R4-proven projection kernel; interleaved qkws[hw][Q160|K160] bf16
//         rows (640B), cols 144..159 of each half stored zero.
// k_attn: R4-proven kernel + ONE change: K staged in LDS (kl[240][168], aliased
//         over xl/wl), so att^T K-frags come from LDS not 64-scattered global
//         rows. f2bf (bitwise RNE) everywhere — NO cvt_pk inline asm (NaN'd 3x).

typedef __bf16 bf16x8 __attribute__((ext_vector_type(8)));
typedef float  f32x4  __attribute__((ext_vector_type(4)));

#define MFMA(a,b,c) __builtin_amdgcn_mfma_f32_16x16x32_bf16((a),(b),(c),0,0,0)

#define QK_ROW 320            // Q cols 0..159 (144+ zero), K cols 160..319 (144+ zero)
#define KL_STRIDE 168         // kl row stride in ushorts (336B: 16B-aligned, 2-way banks)

__device__ __forceinline__ unsigned short f2bf(float f){
  union { float f; unsigned int u; } v; v.f = f;
  unsigned int r = v.u + 0x7FFFu + ((v.u >> 16) & 1u);   // RNE
  return (unsigned short)(r >> 16);
}
// 16B-block XOR swizzle for [rows][256] bf16 LDS tiles (write&read same involution).
__device__ __forceinline__ int swz(int row, int col){
  return row*256 + ((((col >> 3) ^ (row & 7)) << 3) | (col & 7));
}
__device__ __forceinline__ bf16x8 ld_frag_lds(const unsigned short* p, int idx){
  uint4 v = *(const uint4*)(p + idx);
  return __builtin_bit_cast(bf16x8, v);
}
__device__ __forceinline__ bf16x8 ld_frag_b(const void* p){
  uint4 v = *(const uint4*)p;
  return __builtin_bit_cast(bf16x8, v);
}

// D-layout (col=lane&15, rows 4*(lane>>4)+jj per 16-tile) -> operand-frag layout.
__device__ __forceinline__ void repack_frag(const unsigned int* plo, const unsigned int* phi,
                                            uint4* outf, int lane){
  const int nn = lane & 15, hh = lane >> 4;
  const int sla = nn + 32*(hh & 1);
  const int slb = sla + 16;
  const bool up = hh >= 2;
  #pragma unroll
  for (int k = 0; k < 8; ++k){
    unsigned int a0 = (unsigned int)__shfl((int)plo[2*k],   sla);
    unsigned int a1 = (unsigned int)__shfl((int)plo[2*k+1], sla);
    unsigned int b0 = (unsigned int)__shfl((int)phi[2*k],   sla);
    unsigned int b1 = (unsigned int)__shfl((int)phi[2*k+1], sla);
    unsigned int c0 = (unsigned int)__shfl((int)plo[2*k],   slb);
    unsigned int c1 = (unsigned int)__shfl((int)plo[2*k+1], slb);
    unsigned int d0 = (unsigned int)__shfl((int)phi[2*k],   slb);
    unsigned int d1 = (unsigned int)__shfl((int)phi[2*k+1], slb);
    outf[k] = make_uint4(up?a1:a0, up?b1:b0, up?c1:c0, up?d1:d0);
  }
}

// ---------------- kernel 1: QK projections (R1-proven) -----------------------
__global__ __launch_bounds__(512) void k_qk(
    const float* __restrict__ x, const float* __restrict__ wq,
    const float* __restrict__ wk,
    unsigned short* __restrict__ qkws)
{
  __shared__ unsigned short xt [128*256];  // X^T tile [hw][c], swizzled
  __shared__ unsigned short wqs[ 32*256];  // wq rows  [e ][c], swizzled
  __shared__ unsigned short wks[ 32*256];
  const int wg  = blockIdx.x;
  const int b   = wg / 450;
  const int hw0 = (wg % 450) * 128;
  const int tid = threadIdx.x;
  const int lane = tid & 63, wave = tid >> 6;
  const int col  = lane & 15, hi = lane >> 4;

  { // stage X^T (fp32 -> bf16), coalesced reads over hw
    const float* xb = x + (size_t)b * 256 * 57600 + hw0;
    const int hw_l = tid & 127;
    #pragma unroll 4
    for (int i = 0; i < 32; ++i){
      int cp = (tid >> 7) * 32 + i;      // 0..127
      int c  = cp * 2;
      float f0 = xb[(size_t)c     * 57600 + hw_l];
      float f1 = xb[(size_t)(c+1) * 57600 + hw_l];
      *(unsigned int*)(&xt[swz(hw_l, c)]) =
          (unsigned int)f2bf(f0) | ((unsigned int)f2bf(f1) << 16);
    }
  }
  __syncthreads();

  bf16x8 af[8];                          // A-frags: this wave's 16 hw rows
  const int arow = wave*16 + col;
  #pragma unroll
  for (int k = 0; k < 8; ++k)
    af[k] = ld_frag_lds(xt, swz(arow, k*32 + hi*8));

  const size_t orow_base = (size_t)b*57600 + hw0 + wave*16;

  for (int eg = 0; eg < 5; ++eg){        // e-groups of 32 (e_pad=160, zeros>=144)
    __syncthreads();
    for (int i = 0; i < 8; ++i){
      int idx = tid + i*512;             // 0..4095
      int e_l = idx >> 7, c = (idx & 127) * 2;
      int e = eg*32 + e_l;
      float2 vq = make_float2(0.f,0.f), vk = make_float2(0.f,0.f);
      if (e < 144){
        vq = *(const float2*)(wq + (size_t)e*256 + c);
        vk = *(const float2*)(wk + (size_t)e*256 + c);
      }
      *(unsigned int*)(&wqs[swz(e_l, c)]) =
          (unsigned int)f2bf(vq.x) | ((unsigned int)f2bf(vq.y) << 16);
      *(unsigned int*)(&wks[swz(e_l, c)]) =
          (unsigned int)f2bf(vk.x) | ((unsigned int)f2bf(vk.y) << 16);
    }
    __syncthreads();
    #pragma unroll
    for (int etl = 0; etl < 2; ++etl){
      f32x4 aq = {0.f,0.f,0.f,0.f}, ak = {0.f,0.f,0.f,0.f};
      const int el = etl*16 + col;
      #pragma unroll
      for (int k = 0; k < 8; ++k){
        int idx = swz(el, k*32 + hi*8);
        bf16x8 bq = ld_frag_lds(wqs, idx);
        bf16x8 bk = ld_frag_lds(wks, idx);
        aq = MFMA(af[k], bq, aq);
        ak = MFMA(af[k], bk, ak);
      }
      const int e_out = eg*32 + etl*16 + col;
      #pragma unroll
      for (int jj = 0; jj < 4; ++jj){
        size_t row = orow_base + hi*4 + jj;
        qkws[row*QK_ROW + e_out]       = f2bf(aq[jj]);
        qkws[row*QK_ROW + 160 + e_out] = f2bf(ak[jj]);
      }
    }
  }
}

// ---------------- kernel 2: attention + PV + proj + residual -----------------
__global__ __launch_bounds__(512,4) void k_attn(
    const float* __restrict__ x, const float* __restrict__ wproj,
    const unsigned short* __restrict__ qkws, float* __restrict__ out)
{
  // Aliased region S[0..40320): P0/P1: kl[240][168] (80,640B).
  //                             P2+ : xl[128][256] (65,536B) | wl[16][256] (8,192B).
  // hwp LUT outside alias region (960B). Total 81,600B -> still 2 WG/CU.
  __shared__ __align__(16) unsigned short S[40320 + 480];
  unsigned short* kl = S;
  unsigned short* xl = S;
  unsigned short* wl = S + 32768;
  unsigned int*  hwp = (unsigned int*)(S + 40320);
  const int wg = blockIdx.x;
  const int b  = wg >> 8;
  const int th = (wg >> 4) & 15, tw = wg & 15;
  const int h0 = th*15, w0 = tw*15;
  const int tid = threadIdx.x;
  const int lane = tid & 63, wave = tid >> 6;
  const int col  = lane & 15, hi = lane >> 4;
  const size_t xbase = (size_t)b * 256 * 57600;
  const unsigned short* qkb = qkws + (size_t)b * 57600 * QK_ROW;

  if (tid < 240){
    int ms = tid <= 224 ? tid : 224;
    hwp[tid] = (unsigned int)((h0 + ms/15)*240 + w0 + ms%15);
  }
  __syncthreads();

  // ---- P0: stage K rows into kl (coalesced; zeros at e>=144 already in qkws) ----
  for (int i = tid; i < 240*20; i += 512){
    int m = i / 20, eb = i - m*20;
    *(uint4*)(&kl[m*KL_STRIDE + eb*8]) =
        *(const uint4*)(qkb + (size_t)hwp[m]*QK_ROW + 160 + eb*8);
  }
  __syncthreads();

  // ---- P1: att^T strips + lane-local softmax + register repack ----
  uint4 attf[2][8];
  #pragma unroll
  for (int slot = 0; slot < 2; ++slot){
    const int nt = wave + slot*8;
    if (nt < 15){
      const int n  = nt*16 + col;
      const int na = n <= 224 ? n : 224;          // clamp (garbage cols unused)
      const unsigned short* qrow = qkb + (size_t)hwp[na]*QK_ROW;
      bf16x8 qf[5];
      #pragma unroll
      for (int c = 0; c < 5; ++c)
        qf[c] = ld_frag_b(qrow + c*32 + hi*8);
      f32x4 at[15];
      #pragma unroll
      for (int T = 0; T < 15; ++T){
        f32x4 acc = {0.f,0.f,0.f,0.f};
        #pragma unroll
        for (int c = 0; c < 5; ++c){
          bf16x8 kf = ld_frag_lds(kl, (T*16 + col)*KL_STRIDE + c*32 + hi*8);
          acc = MFMA(kf, qf[c], acc);             // att^T[m][n]
        }
        at[T] = acc;
      }
      const float sc = 0.12022458674074695f;      // log2(e)/12
      float M = -3.0e38f;
      #pragma unroll
      for (int T = 0; T < 15; ++T){
        #pragma unroll
        for (int jj = 0; jj < 4; ++jj){
          int m = T*16 + hi*4 + jj;
          if (m <= 224) M = fmaxf(M, at[T][jj]*sc);
        }
      }
      M = fmaxf(M, __shfl_xor(M, 16));
      M = fmaxf(M, __shfl_xor(M, 32));
      float Ssum = 0.f;
      #pragma unroll
      for (int T = 0; T < 15; ++T){
        #pragma unroll
        for (int jj = 0; jj < 4; ++jj){
          int m = T*16 + hi*4 + jj;
          float v = (m <= 224) ? exp2f(at[T][jj]*sc - M) : 0.f;
          at[T][jj] = v; Ssum += v;
        }
      }
      Ssum += __shfl_xor(Ssum, 16);
      Ssum += __shfl_xor(Ssum, 32);
      const float inv = 1.0f / Ssum;
      unsigned int plo[16], phi[16];
      #pragma unroll
      for (int T = 0; T < 15; ++T){
        plo[T] = (unsigned int)f2bf(at[T][0]*inv) | ((unsigned int)f2bf(at[T][1]*inv) << 16);
        phi[T] = (unsigned int)f2bf(at[T][2]*inv) | ((unsigned int)f2bf(at[T][3]*inv) << 16);
      }
      plo[15] = 0u; phi[15] = 0u;
      repack_frag(plo, phi, attf[slot], lane);
    }
  }

  // ---- P2/P3: X staged by c-halves (xl[128][256] swizzled, m>224 zero;
  //             aliases kl after the loop-head barrier); PV partials bf16 ----
  unsigned int ylo[2][16], yhi[2][16];
  #pragma unroll
  for (int half = 0; half < 2; ++half){
    __syncthreads();                         // previous readers (P1 kl / PV) done
    for (int i = tid; i < 128*128; i += 512){
      int c = i >> 7, m = (i & 127)*2;
      int m0 = m <= 224 ? m : 224;           // clamped LUT index (no OOB)
      float f0 = (m     <= 224) ? x[xbase + (size_t)(half*128 + c)*57600 + hwp[m0]]   : 0.f;
      float f1 = (m + 1 <= 224) ? x[xbase + (size_t)(half*128 + c)*57600 + hwp[m0+1]] : 0.f;
      *(unsigned int*)(&xl[swz(c, m)]) =
          (unsigned int)f2bf(f0) | ((unsigned int)f2bf(f1) << 16);
    }
    __syncthreads();
    #pragma unroll
    for (int slot = 0; slot < 2; ++slot){
      const int nt = wave + slot*8;
      if (nt < 15){
        #pragma unroll
        for (int ct = 0; ct < 8; ++ct){
          f32x4 acc = {0.f,0.f,0.f,0.f};
          #pragma unroll
          for (int k = 0; k < 8; ++k){
            bf16x8 xf = ld_frag_lds(xl, swz(ct*16 + col, k*32 + hi*8));
            acc = MFMA(xf, __builtin_bit_cast(bf16x8, attf[slot][k]), acc);
          }
          ylo[slot][half*8 + ct] = (unsigned int)f2bf(acc[0]) | ((unsigned int)f2bf(acc[1]) << 16);
          yhi[slot][half*8 + ct] = (unsigned int)f2bf(acc[2]) | ((unsigned int)f2bf(acc[3]) << 16);
        }
      }
    }
  }

  uint4 y1f[2][8];
  #pragma unroll
  for (int slot = 0; slot < 2; ++slot){
    const int nt = wave + slot*8;
    if (nt < 15)
      repack_frag(ylo[slot], yhi[slot], y1f[slot], lane);
  }

  // ---- P4: projection (wproj fp32 -> wl sixteenths) + fp32 residual ----
  #pragma unroll 1
  for (int oe = 0; oe < 16; ++oe){
    __syncthreads();                          // prev chunk's readers done
    for (int i = tid; i < 16*128; i += 512){
      int olr = i >> 7, c = (i & 127)*2;
      const float* wr = wproj + (size_t)(oe*16 + olr)*256 + c;
      *(unsigned int*)(&wl[swz(olr, c)]) =
          (unsigned int)f2bf(wr[0]) | ((unsigned int)f2bf(wr[1]) << 16);
    }
    __syncthreads();
    bf16x8 awf[8];
    #pragma unroll
    for (int k = 0; k < 8; ++k)
      awf[k] = ld_frag_lds(wl, swz(col, k*32 + hi*8));
    #pragma unroll
    for (int slot = 0; slot < 2; ++slot){
      const int nt = wave + slot*8;
      if (nt < 15){
        f32x4 y2 = {0.f,0.f,0.f,0.f};
        #pragma unroll
        for (int k = 0; k < 8; ++k)
          y2 = MFMA(awf[k], __builtin_bit_cast(bf16x8, y1f[slot][k]), y2);
        const int n = nt*16 + col;
        if (n <= 224){
          const size_t pix = hwp[n];
          #pragma unroll
          for (int jj = 0; jj < 4; ++jj){
            int o = oe*16 + hi*4 + jj;
            const size_t idx = xbase + (size_t)o*57600 + pix;
            out[idx] = y2[jj] + x[idx];
          }
        }
      }
    }
  }
}

extern "C" void kernel_launch(void* const* d_in, const int* in_sizes, int n_in,
                              void* d_out, int out_size, void* d_ws, size_t ws_size,
                              hipStream_t stream)
{
  const float* x     = (const float*)d_in[0];
  const float* wq    = (const float*)d_in[1];
  const float* wk    = (const float*)d_in[2];
  const float* wproj = (const float*)d_in[3];
  float* out = (float*)d_out;
  // workspace: qkws rows 8*57600 x 320 bf16 = 294,912,000 B
  unsigned short* qkws = (unsigned short*)d_ws;
  (void)in_sizes; (void)n_in; (void)out_size; (void)ws_size;

  k_qk  <<<dim3(3600), dim3(512), 0, stream>>>(x, wq, wk, qkws);
  k_attn<<<dim3(2048), dim3(512), 0, stream>>>(x, wproj, qkws, out);
}